// Round 7
// baseline (227.073 us; speedup 1.0000x reference)
//
#include <hip/hip_runtime.h>
#include <math.h>

#define B_NUM 4
#define S_LEN 2048
#define D_DIM 1024
#define H_NUM 16
#define W_DIM 64

typedef float4 f4;
typedef _Float16 f16;
typedef f16 f16x8 __attribute__((ext_vector_type(8)));
typedef f16 f16x4 __attribute__((ext_vector_type(4)));
typedef float floatx4 __attribute__((ext_vector_type(4)));

#define GLOAD_LDS16(gp, lp)                                                     \
    __builtin_amdgcn_global_load_lds(                                           \
        (const __attribute__((address_space(1))) void*)(gp),                    \
        (__attribute__((address_space(3))) void*)(lp), 16, 0, 0)

#define N_TILES 1536   // 24 n-tiles x 64 m-tiles
#define GEMM_BLOCKS 1280

// ---------------------------------------------------------------------------
// Merged pre-pass (one launch, block-id ranges):
//   blocks 0..3      : per-batch mask compaction (+ ticket reset in block 0)
//   blocks 4..771    : W[k][n] fp32 -> W^T[n][k] f16 (64x64 tiles)
//   blocks 772..8963 : cast x fp32 -> f16
// ---------------------------------------------------------------------------
__global__ __launch_bounds__(256) void prep_kernel(
    const float* __restrict__ x,
    const float* __restrict__ Wq, const float* __restrict__ Wk,
    const float* __restrict__ Wv, const int* __restrict__ mask,
    f16* __restrict__ x16, f16* __restrict__ wt16,
    short* __restrict__ fwdmap, int* __restrict__ cnt, int* __restrict__ ticket)
{
    __shared__ float ts[64][68];
    const int bid = blockIdx.x;
    const int tid = threadIdx.x;

    if (bid < 4) {
        // ---- compaction (kept = mask==0) ----
        int* sc = (int*)&ts[0][0];
        const int b  = bid;
        const int t0 = tid * 8;
        if (bid == 0 && tid == 0) *ticket = 0;

#pragma unroll
        for (int j = 0; j < 8; ++j) fwdmap[b * S_LEN + t0 + j] = 0;

        int kept[8], c = 0;
#pragma unroll
        for (int j = 0; j < 8; ++j) {
            kept[j] = (mask[b * S_LEN + t0 + j] == 0);
            c += kept[j];
        }
        sc[tid] = c;
        __syncthreads();
        for (int off = 1; off < 256; off <<= 1) {
            int add = (tid >= off) ? sc[tid - off] : 0;
            __syncthreads();
            sc[tid] += add;
            __syncthreads();
        }
        int base = sc[tid] - c;
#pragma unroll
        for (int j = 0; j < 8; ++j)
            if (kept[j]) fwdmap[b * S_LEN + (base++)] = (short)(t0 + j);
        if (tid == 255) {
            cnt[b * 4 + 0] = sc[255];
            cnt[b * 4 + 1] = (sc[255] + 63) & ~63;
            cnt[b * 4 + 2] = (sc[255] + 127) & ~127;
        }
    } else if (bid < 4 + 768) {
        // ---- W transpose ----
        const int tb = bid - 4;
        const int k0 = (tb & 15) * 64;
        const int n0 = ((tb >> 4) & 15) * 64;
        const int z  = tb >> 8;
        const float* Wsel = (z == 0) ? Wq : (z == 1) ? Wk : Wv;
        f16* outp = wt16 + (size_t)z * D_DIM * D_DIM;

        const int r  = tid >> 4;
        const int c4 = (tid & 15) * 4;
#pragma unroll
        for (int i = 0; i < 4; ++i) {
            f4 t = *(const f4*)&Wsel[(size_t)(k0 + r + i * 16) * D_DIM + n0 + c4];
            *(f4*)&ts[r + i * 16][c4] = t;
        }
        __syncthreads();
#pragma unroll
        for (int i = 0; i < 4; ++i) {
            int idx = tid + i * 256;
            int nl = idx >> 4;
            int k4 = (idx & 15) * 4;
            f16x4 o;
#pragma unroll
            for (int j = 0; j < 4; ++j) o[j] = (f16)ts[k4 + j][nl];
            *(f16x4*)&outp[(size_t)(n0 + nl) * D_DIM + k0 + k4] = o;
        }
    } else {
        // ---- x cast ----
        const size_t i = (size_t)(bid - 772) * 256 + tid;
        f4 t = *(const f4*)&x[i * 4];
        f16x4 o;
        o[0] = (f16)t.x; o[1] = (f16)t.y; o[2] = (f16)t.z; o[3] = (f16)t.w;
        *(f16x4*)&x16[i * 4] = o;
    }
}

// ---------------------------------------------------------------------------
// QKV GEMM, f16 MFMA, BK=64, XOR-swizzled LDS (conflict-free — R6 verified),
// PERSISTENT blocks pulling tile ids from an atomic ticket (load balance:
// masked K/V tiles are skipped cheaply and their slots backfilled).
// Tile id t: nt = t%24 (n fastest for L2 A-reuse), mt = t/24.
//   Q -> (B,H,S,W) * 0.125 ; K -> (B,H,jc,W) ; V -> (B,H,W,jc)
// ---------------------------------------------------------------------------
__global__ __launch_bounds__(256) void qkv_mfma_kernel(
    const f16* __restrict__ x16, const f16* __restrict__ wt16,
    const float* __restrict__ bq, const float* __restrict__ bk,
    const float* __restrict__ bv, const short* __restrict__ fwdmap,
    const int* __restrict__ cnt, int* __restrict__ ticket,
    f16* __restrict__ Qo, f16* __restrict__ Ko, f16* __restrict__ Vo)
{
    __shared__ f16 As[128 * 64];
    __shared__ f16 Bs[128 * 64];
    __shared__ int s_t;

    const int tid  = threadIdx.x;
    const int lane = tid & 63;
    const int wid  = tid >> 6;
    const int lx   = lane & 15;
    const int quad = lane >> 4;
    const int wm   = wid >> 1;
    const int wn   = wid & 1;

    const int srow = lane >> 3;               // 0..7 within 8-row chunk
    const int scw  = ((lane & 7) ^ srow) * 8; // swizzled source k-chunk

    for (;;) {
        __syncthreads();                      // LDS reuse + s_t protect
        if (tid == 0) s_t = atomicAdd(ticket, 1);
        __syncthreads();
        const int t = s_t;
        if (t >= N_TILES) return;             // block-uniform

        const int nt    = t % 24;
        const int mt    = t / 24;
        const int midx  = nt >> 3;
        const int c0    = (nt & 7) * 128;
        const int r0    = mt * 128;
        const int bB    = r0 >> 11;
        const int r0loc = r0 & (S_LEN - 1);

        if (midx > 0 && r0loc >= cnt[bB * 4 + 2]) continue;   // masked K/V tile

        const f16* Bg = wt16 + (size_t)midx * D_DIM * D_DIM + (size_t)c0 * D_DIM;

        int arows[4];
#pragma unroll
        for (int it = 0; it < 4; ++it) {
            int rl = (wid * 4 + it) * 8 + srow;
            arows[it] = (midx == 0)
                ? (r0 + rl)
                : (bB * S_LEN + (int)fwdmap[bB * S_LEN + r0loc + rl]);
        }

        floatx4 acc[4][4];
#pragma unroll
        for (int a = 0; a < 4; ++a)
#pragma unroll
            for (int b = 0; b < 4; ++b) { acc[a][b][0]=0.f; acc[a][b][1]=0.f; acc[a][b][2]=0.f; acc[a][b][3]=0.f; }

        for (int k0 = 0; k0 < D_DIM; k0 += 64) {
            __syncthreads();
#pragma unroll
            for (int it = 0; it < 4; ++it) {
                int chunk = wid * 4 + it;
                GLOAD_LDS16(&x16[(size_t)arows[it] * D_DIM + k0 + scw], &As[chunk * 512]);
                GLOAD_LDS16(&Bg[(size_t)(chunk * 8 + srow) * D_DIM + k0 + scw], &Bs[chunk * 512]);
            }
            __syncthreads();

#pragma unroll
            for (int kh = 0; kh < 2; ++kh) {
                const int csw = ((kh * 4 + quad) ^ (lx & 7)) * 8;
                f16x8 af[4], bf[4];
#pragma unroll
                for (int tm = 0; tm < 4; ++tm)
                    af[tm] = *(const f16x8*)&As[(wm * 64 + tm * 16 + lx) * 64 + csw];
#pragma unroll
                for (int tn = 0; tn < 4; ++tn)
                    bf[tn] = *(const f16x8*)&Bs[(wn * 64 + tn * 16 + lx) * 64 + csw];
#pragma unroll
                for (int tm = 0; tm < 4; ++tm)
#pragma unroll
                    for (int tn = 0; tn < 4; ++tn)
                        acc[tm][tn] = __builtin_amdgcn_mfma_f32_16x16x32_f16(
                            af[tm], bf[tn], acc[tm][tn], 0, 0, 0);
            }
        }

        const float* bp = (midx == 0) ? bq : (midx == 1) ? bk : bv;
        float bias[4];
#pragma unroll
        for (int tn = 0; tn < 4; ++tn)
            bias[tn] = bp[c0 + wn * 64 + tn * 16 + lx];

        if (midx == 0) {
#pragma unroll
            for (int tm = 0; tm < 4; ++tm) {
                int s = r0loc + wm * 64 + tm * 16 + quad * 4;
#pragma unroll
                for (int tn = 0; tn < 4; ++tn) {
                    int gc = c0 + wn * 64 + tn * 16 + lx;
                    int h = gc >> 6, w = gc & 63;
                    size_t base = (((size_t)(bB * H_NUM + h)) * S_LEN + s) * W_DIM + w;
#pragma unroll
                    for (int rr = 0; rr < 4; ++rr)
                        Qo[base + (size_t)rr * W_DIM] =
                            (f16)((acc[tm][tn][rr] + bias[tn]) * 0.125f);
                }
            }
        } else if (midx == 1) {
#pragma unroll
            for (int tm = 0; tm < 4; ++tm) {
                int jc = r0loc + wm * 64 + tm * 16 + quad * 4;
#pragma unroll
                for (int tn = 0; tn < 4; ++tn) {
                    int gc = c0 + wn * 64 + tn * 16 + lx;
                    int h = gc >> 6, w = gc & 63;
                    size_t base = (((size_t)(bB * H_NUM + h)) * S_LEN + jc) * W_DIM + w;
#pragma unroll
                    for (int rr = 0; rr < 4; ++rr)
                        Ko[base + (size_t)rr * W_DIM] = (f16)(acc[tm][tn][rr] + bias[tn]);
                }
            }
        } else {
#pragma unroll
            for (int tm = 0; tm < 4; ++tm) {
                int jc = r0loc + wm * 64 + tm * 16 + quad * 4;
#pragma unroll
                for (int tn = 0; tn < 4; ++tn) {
                    int gc = c0 + wn * 64 + tn * 16 + lx;
                    int h = gc >> 6, w = gc & 63;
                    f16x4 v;
#pragma unroll
                    for (int rr = 0; rr < 4; ++rr) v[rr] = (f16)(acc[tm][tn][rr] + bias[tn]);
                    *(f16x4*)&Vo[(((size_t)(bB * H_NUM + h)) * W_DIM + w) * S_LEN + jc] = v;
                }
            }
        }
    }
}

// ---------------------------------------------------------------------------
// Flash attention over COMPACTED keys, S^T formulation, 2 q-tiles per wave.
// Unchanged from round 6.
// ---------------------------------------------------------------------------
#define LSTR 72

__global__ __launch_bounds__(256) void attn_kernel(
    const f16* __restrict__ Q, const f16* __restrict__ Kc,
    const f16* __restrict__ Vct, const int* __restrict__ cnt,
    float* __restrict__ out)
{
    __shared__ f16 Ks[64][LSTR];
    __shared__ f16 Vs[64][LSTR];

    const int tid  = threadIdx.x;
    const int lane = tid & 63;
    const int wid  = tid >> 6;
    const int lx   = lane & 15;
    const int quad = lane >> 4;
    const int qt = blockIdx.x, h = blockIdx.y, bb = blockIdx.z;

    const int count = cnt[bb * 4 + 0];
    const int scp   = cnt[bb * 4 + 1];

    const size_t hoff = ((size_t)(bb * H_NUM + h)) * S_LEN * W_DIM;
    const f16* Qg = Q + hoff + (size_t)qt * 128 * W_DIM;
    const f16* Kg = Kc + hoff;
    const f16* Vg = Vct + hoff;

    f16x8 qb[2][2];
#pragma unroll
    for (int u = 0; u < 2; ++u) {
        int qrow = u * 64 + wid * 16 + lx;
        qb[u][0] = *(const f16x8*)&Qg[(size_t)qrow * W_DIM + quad * 8];
        qb[u][1] = *(const f16x8*)&Qg[(size_t)qrow * W_DIM + 32 + quad * 8];
    }

    floatx4 o[2][4];
    float lsum[2] = {0.f, 0.f};
#pragma unroll
    for (int u = 0; u < 2; ++u)
#pragma unroll
        for (int wb = 0; wb < 4; ++wb) { o[u][wb][0]=0.f; o[u][wb][1]=0.f; o[u][wb][2]=0.f; o[u][wb][3]=0.f; }

    for (int k0 = 0; k0 < scp; k0 += 64) {
        __syncthreads();
#pragma unroll
        for (int it = 0; it < 2; ++it) {
            int idx = tid + it * 256;
            int row = idx >> 3, c8 = (idx & 7) * 8;
            *(f16x8*)&Ks[row][c8] = *(const f16x8*)&Kg[(size_t)(k0 + row) * W_DIM + c8];
            *(f16x8*)&Vs[row][c8] = *(const f16x8*)&Vg[(size_t)row * S_LEN + k0 + c8];
        }
        __syncthreads();

        const bool tail = (k0 + 64 > count);

        f16x4 pb[2][4];
#pragma unroll
        for (int n = 0; n < 4; ++n) {
            f16x8 ka0 = *(const f16x8*)&Ks[n * 16 + lx][quad * 8];
            f16x8 ka1 = *(const f16x8*)&Ks[n * 16 + lx][32 + quad * 8];
            const int kb = k0 + n * 16 + quad * 4;
#pragma unroll
            for (int u = 0; u < 2; ++u) {
                floatx4 s; s[0]=0.f; s[1]=0.f; s[2]=0.f; s[3]=0.f;
                s = __builtin_amdgcn_mfma_f32_16x16x32_f16(ka0, qb[u][0], s, 0, 0, 0);
                s = __builtin_amdgcn_mfma_f32_16x16x32_f16(ka1, qb[u][1], s, 0, 0, 0);
                float p[4], ls = 0.f;
                if (tail) {
#pragma unroll
                    for (int r = 0; r < 4; ++r) {
                        float sv = (kb + r < count) ? s[r] : -1.0e4f;
                        p[r] = __expf(sv); ls += p[r];
                    }
                } else {
#pragma unroll
                    for (int r = 0; r < 4; ++r) { p[r] = __expf(s[r]); ls += p[r]; }
                }
                lsum[u] += ls;
#pragma unroll
                for (int r = 0; r < 4; ++r) pb[u][n][r] = (f16)p[r];
            }
        }

#pragma unroll
        for (int wb = 0; wb < 4; ++wb) {
#pragma unroll
            for (int n = 0; n < 4; ++n) {
                f16x4 va = *(const f16x4*)&Vs[wb * 16 + lx][n * 16 + quad * 4];
#pragma unroll
                for (int u = 0; u < 2; ++u)
                    o[u][wb] = __builtin_amdgcn_mfma_f32_16x16x16f16(va, pb[u][n], o[u][wb], 0, 0, 0);
            }
        }
    }

#pragma unroll
    for (int u = 0; u < 2; ++u) {
        float ls = lsum[u];
        ls += __shfl_xor(ls, 16);
        ls += __shfl_xor(ls, 32);
        const float rl = 1.0f / ls;
        const int q = qt * 128 + u * 64 + wid * 16 + lx;
        const size_t base = ((size_t)bb * S_LEN + q) * D_DIM + h * W_DIM;
#pragma unroll
        for (int wb = 0; wb < 4; ++wb) {
            f4 r;
            r.x = o[u][wb][0] * rl;
            r.y = o[u][wb][1] * rl;
            r.z = o[u][wb][2] * rl;
            r.w = o[u][wb][3] * rl;
            *(f4*)&out[base + wb * 16 + quad * 4] = r;
        }
    }
}

// ---------------------------------------------------------------------------
extern "C" void kernel_launch(void* const* d_in, const int* in_sizes, int n_in,
                              void* d_out, int out_size, void* d_ws, size_t ws_size,
                              hipStream_t stream)
{
    const float* x    = (const float*)d_in[0];
    const float* Wq   = (const float*)d_in[1];
    const float* bq   = (const float*)d_in[2];
    const float* Wk   = (const float*)d_in[3];
    const float* bk   = (const float*)d_in[4];
    const float* Wv   = (const float*)d_in[5];
    const float* bv   = (const float*)d_in[6];
    const int*   mask = (const int*)d_in[7];
    float* out = (float*)d_out;

    const size_t per = (size_t)B_NUM * H_NUM * S_LEN * W_DIM;  // 8,388,608
    f16*   Q      = (f16*)d_ws;
    f16*   Kc     = Q + per;
    f16*   Vct    = Kc + per;
    f16*   x16    = Vct + per;
    f16*   wt16   = x16 + (size_t)(B_NUM * S_LEN) * D_DIM;
    int*   cnt    = (int*)(wt16 + (size_t)3 * D_DIM * D_DIM);
    int*   ticket = cnt + 4 * B_NUM;
    short* fwdmap = (short*)(ticket + 4);

    prep_kernel<<<4 + 768 + 8192, 256, 0, stream>>>(
        x, Wq, Wk, Wv, mask, x16, wt16, fwdmap, cnt, ticket);
    qkv_mfma_kernel<<<GEMM_BLOCKS, 256, 0, stream>>>(
        x16, wt16, bq, bk, bv, fwdmap, cnt, ticket, Q, Kc, Vct);
    attn_kernel<<<dim3(S_LEN / 128, H_NUM, B_NUM), 256, 0, stream>>>(
        Q, Kc, Vct, cnt, out);
}